// Round 11
// baseline (1652.122 us; speedup 1.0000x reference)
//
#include <hip/hip_runtime.h>

// Problem constants
#define NB    16
#define NT    3
#define NCTX  2048
#define NLAT  512
#define DIMV  512
#define HALFD 256
#define NFEAT 51
#define NBT   48
#define MROWS 24576    // NBT*NLAT
#define GRP   6        // bt per context group
#define NGRP  8
#define GROWS 12288    // GRP*NCTX
#define FUSED_BLKS (NB + GROWS/16 + 4096)   // fps + g0 embed + 5 transposes

typedef unsigned short bfu;   // bf16 storage as raw bits
typedef short bf16x8 __attribute__((ext_vector_type(8)));   // 8 bf16 = 4 VGPR
typedef float f32x4  __attribute__((ext_vector_type(4)));   // MFMA 16x16 acc
typedef float f32x2  __attribute__((ext_vector_type(2)));   // packed fp32 pair

__device__ __forceinline__ float bf2f(bfu u){ return __uint_as_float(((unsigned int)u) << 16); }
__device__ __forceinline__ bfu f2bf(float f){
  unsigned int u = __float_as_uint(f);
  u += 0x7FFFu + ((u >> 16) & 1u);          // RNE
  return (bfu)(u >> 16);
}
__device__ __forceinline__ float loadE(const float* p){ return *p; }
__device__ __forceinline__ float loadE(const bfu* p){ return bf2f(*p); }
__device__ __forceinline__ void storeE(float* p, float v){ *p = v; }
__device__ __forceinline__ void storeE(bfu* p, float v){ *p = f2bf(v); }
__device__ __forceinline__ bfu to_bfu(float f){ return f2bf(f); }
__device__ __forceinline__ bfu to_bfu(bfu u){ return u; }

// Async 16B global->LDS DMA. LDS dest = wave-uniform base + lane*16 (linear!)
// so swizzled layouts are achieved by pre-swizzling the per-lane GLOBAL
// source address (m173 pattern), never the LDS dest.
#define GLD16(gp, lp) __builtin_amdgcn_global_load_lds(                       \
    (const __attribute__((address_space(1))) unsigned int*)(gp),              \
    (__attribute__((address_space(3))) unsigned int*)(lp), 16, 0, 0)

// XOR chunk swizzle key for a [*][KSTEP] bf16 LDS tile (16B chunks).
template<int KSTEP>
__device__ __forceinline__ int swzr(int r){
  constexpr int CPR = KSTEP / 8;
  return (KSTEP == 32) ? ((r >> 1) & 3) : (r & (CPR - 1));
}

// ---------------------------------------------------------------------------
// FPS core: FOUR waves per batch, 512 pts/wave register-resident.
// R10: winner COORDS ride the merge record -- after the DPP argmax the
// owning lane ((ib&63)==lane, unique in wave) writes x/y/z (register bits,
// static-index cndmask tree) alongside lane-63's (v,idx). The merge read
// then yields both `last` and its coords, deleting the pts[] table and its
// ~120cy broadcast read from the serial chain (R6-R10: the chain is the
// whole cost; VALU issue is minor).
// Tie-breaks preserve numpy first-max exactly: index-ordered in-lane
// merges, DPP carries global idx (tie -> lower), wave ranges ascending so
// strict > keeps the lowest index. Distance expressions and the parity
// double-buffer protocol are byte-identical to the R9/R10 passing builds.
// ---------------------------------------------------------------------------
#define DPP_ARGMAX_STAGE(CTRL)                                                \
  {                                                                           \
    const int svb = __builtin_amdgcn_update_dpp(vb, vb, CTRL, 0xF, 0xF, false); \
    const int sib = __builtin_amdgcn_update_dpp(ib, ib, CTRL, 0xF, 0xF, false); \
    const float sv = __int_as_float(svb);                                     \
    const float cv = __int_as_float(vb);                                      \
    if (sv > cv || (sv == cv && sib < ib)){ vb = svb; ib = sib; }             \
  }

__device__ __forceinline__ void fps_body(int b, int tid, const float* __restrict__ pc,
                                         int* __restrict__ idx_out,
                                         float4 (*xyz)[4], int2 (*vi)[4]){
  const int lane = tid & 63, w = tid >> 6;
  const int wbase = w << 9;               // wave owns [512w, 512w+512)
  const float* src = pc + (size_t)b * (NT * NCTX * 3);

  // Slot s (0..7) = point p = wbase + (s<<6) + lane. Coords + running
  // min-dists all register-resident; pair j holds slots 2j (lo), 2j+1 (hi).
  f32x2 x2[4], y2[4], z2[4], d2[4];
  #pragma unroll
  for (int j = 0; j < 4; ++j){
    #pragma unroll
    for (int h = 0; h < 2; ++h){
      const int p = wbase + ((2 * j + h) << 6) + lane;
      x2[j][h] = src[p * 3 + 0];
      y2[j][h] = src[p * 3 + 1];
      z2[j][h] = src[p * 3 + 2];
    }
    d2[j][0] = 1e10f; d2[j][1] = 1e10f;
  }
  if (tid == 0){
    idx_out[b * NLAT] = 0;
    // point 0 = wave 0, slot 0, lane 0 -> its coords seed the first step
    xyz[0][0] = make_float4(x2[0][0], y2[0][0], z2[0][0], 0.f);
  }
  __syncthreads();
  float4 lp = xyz[0][0];                  // uniform addr -> LDS broadcast

  for (int step = 1; step < NLAT; ++step){
    // distance update: pure packed VALU, identical expressions to the
    // proven bit-exact version.
    #pragma unroll
    for (int j = 0; j < 4; ++j){
      const f32x2 dx = x2[j] - lp.x;
      const f32x2 dy = y2[j] - lp.y;
      const f32x2 dz = z2[j] - lp.z;
      const f32x2 dd = (dx * dx + dy * dy) + dz * dz;
      f32x2 nd;
      nd[0] = fminf(d2[j][0], dd[0]);
      nd[1] = fminf(d2[j][1], dd[1]);
      d2[j] = nd;
    }

    // in-lane argmax over 8 slots, adjacent-pair tree (index-ordered
    // merges: strict > keeps the lowest index on ties).
    float av[4]; int as_[4];
    #pragma unroll
    for (int j = 0; j < 4; ++j){
      const float lo = d2[j][0], hi = d2[j][1];
      const bool t = hi > lo;
      av[j]  = t ? hi : lo;
      as_[j] = t ? 2 * j + 1 : 2 * j;
    }
    #pragma unroll
    for (int wdt = 2; wdt; wdt >>= 1){
      #pragma unroll
      for (int j = 0; j < wdt; ++j){
        const float lv = av[2 * j], rv = av[2 * j + 1];
        const int   li = as_[2 * j], ri = as_[2 * j + 1];
        const bool t = rv > lv;
        av[j]  = t ? rv : lv;
        as_[j] = t ? ri : li;
      }
    }

    // cross-lane argmax on (value, GLOBAL index); ties -> lower index
    int vb = __float_as_int(av[0]);
    int ib = wbase + (as_[0] << 6) + lane;
    DPP_ARGMAX_STAGE(0x111)   // row_shr:1
    DPP_ARGMAX_STAGE(0x112)   // row_shr:2
    DPP_ARGMAX_STAGE(0x114)   // row_shr:4
    DPP_ARGMAX_STAGE(0x118)   // row_shr:8
    DPP_ARGMAX_STAGE(0x142)   // row_bcast:15
    DPP_ARGMAX_STAGE(0x143)   // row_bcast:31

    // record: lane 63 writes (v, idx); the owning lane writes the winner's
    // coords (static-index select tree -- no runtime indexing, rule #20).
    const int par = step & 1;
    if (lane == 63) vi[par][w] = make_int2(vb, ib);
    if ((ib & 63) == lane){
      const int s = (ib >> 6) & 7;
      const bool b0 = (s & 1) != 0, b1 = (s & 2) != 0, b2 = (s & 4) != 0;
      const float xa = b0 ? x2[0][1] : x2[0][0];
      const float xb = b0 ? x2[1][1] : x2[1][0];
      const float xc = b0 ? x2[2][1] : x2[2][0];
      const float xd = b0 ? x2[3][1] : x2[3][0];
      const float ya = b0 ? y2[0][1] : y2[0][0];
      const float yb = b0 ? y2[1][1] : y2[1][0];
      const float yc = b0 ? y2[2][1] : y2[2][0];
      const float yd = b0 ? y2[3][1] : y2[3][0];
      const float za = b0 ? z2[0][1] : z2[0][0];
      const float zb = b0 ? z2[1][1] : z2[1][0];
      const float zc = b0 ? z2[2][1] : z2[2][0];
      const float zd = b0 ? z2[3][1] : z2[3][0];
      const float xe = b1 ? xb : xa, xf = b1 ? xd : xc;
      const float ye = b1 ? yb : ya, yf = b1 ? yd : yc;
      const float ze = b1 ? zb : za, zf = b1 ? zd : zc;
      xyz[par][w] = make_float4(b2 ? xf : xe, b2 ? yf : ye, b2 ? zf : ze, 0.f);
    }
    __syncthreads();

    // merge: read all 4 records; sequential strict-> select (wave ranges
    // ascending -> numpy tie-break). Parity buffer -> no second barrier.
    const int2 r0 = vi[par][0], r1 = vi[par][1], r2 = vi[par][2], r3 = vi[par][3];
    const float4 c0 = xyz[par][0], c1 = xyz[par][1], c2 = xyz[par][2], c3 = xyz[par][3];
    float bv = __int_as_float(r0.x); int bi = r0.y;
    float bx = c0.x, by = c0.y, bz = c0.z;
    { const float v1 = __int_as_float(r1.x);
      if (v1 > bv){ bv = v1; bi = r1.y; bx = c1.x; by = c1.y; bz = c1.z; } }
    { const float v2 = __int_as_float(r2.x);
      if (v2 > bv){ bv = v2; bi = r2.y; bx = c2.x; by = c2.y; bz = c2.z; } }
    { const float v3 = __int_as_float(r3.x);
      if (v3 > bv){ bv = v3; bi = r3.y; bx = c3.x; by = c3.y; bz = c3.z; } }
    lp = make_float4(bx, by, bz, 0.f);
    if (tid == 0) idx_out[b * NLAT + step] = bi;
  }
}

// ---------------------------------------------------------------------------
// Embed body: gather + point_embed x2 + layernorm -> bf16. 16 points/block.
// Phase-1 trig parallelized over all 256 threads (bit-exact redistribution).
// ---------------------------------------------------------------------------
template<bool GATHER, bool WRITE_EMB>
__device__ __forceinline__ void embed_body(
    int bid, int tid,
    const float* __restrict__ pc, const float* __restrict__ pc2,
    const int* __restrict__ idx,
    const float* __restrict__ basis, const float* __restrict__ pe_w,
    const float* __restrict__ pe_b,
    const float* __restrict__ ln_g, const float* __restrict__ ln_b,
    bfu* __restrict__ emb, bfu* __restrict__ lnout, int nppbt,
    float (*feat)[16][NFEAT + 1], float (*outb)[DIMV])
{
  const int p0 = bid << 4;

  if (tid < 32){
    const int s = tid >> 4, p = tid & 15;
    const int gp = p0 + p;
    const int bt = gp / nppbt;
    const int n  = gp - bt * nppbt;
    const int bb = bt / NT;
    const int srcn = GATHER ? idx[bb * NLAT + n] : n;
    const float* sp = (s ? pc2 : pc) + ((size_t)bt * NCTX + srcn) * 3;
    feat[s][p][48] = sp[0]; feat[s][p][49] = sp[1]; feat[s][p][50] = sp[2];
  }
  __syncthreads();

  #pragma unroll
  for (int t = 0; t < 3; ++t){
    const int wk  = tid * 3 + t;          // [0,768): (s*16+p)*24 + e
    const int spq = wk / 24;
    const int e   = wk - spq * 24;
    const int s = spq >> 4, p = spq & 15;
    const float x0 = feat[s][p][48], x1 = feat[s][p][49], x2 = feat[s][p][50];
    const float pr = __fadd_rn(__fadd_rn(__fmul_rn(x0, basis[e]),
                                         __fmul_rn(x1, basis[24 + e])),
                               __fmul_rn(x2, basis[48 + e]));
    feat[s][p][e]      = sinf(pr);
    feat[s][p][24 + e] = cosf(pr);
  }
  __syncthreads();

  {
    float w[NFEAT];
    #pragma unroll
    for (int k = 0; k < NFEAT; ++k) w[k] = pe_w[k * HALFD + tid];
    const float bv = pe_b[tid];
    #pragma unroll
    for (int half = 0; half < 2; ++half){
      for (int p = 0; p < 16; ++p){
        float acc = bv;
        #pragma unroll
        for (int k = 0; k < NFEAT; ++k) acc = fmaf(feat[half][p][k], w[k], acc);
        outb[p][half * HALFD + tid] = acc;
      }
    }
  }
  __syncthreads();

  const int lane = tid & 63, wv = tid >> 6;
  for (int pp = 0; pp < 4; ++pp){
    const int p = (wv << 2) + pp;
    const size_t gp = (size_t)p0 + p;
    float x[8];
    #pragma unroll
    for (int j = 0; j < 8; ++j) x[j] = outb[p][lane + (j << 6)];
    float s = 0.f;
    #pragma unroll
    for (int j = 0; j < 8; ++j) s += x[j];
    for (int o = 32; o; o >>= 1) s += __shfl_xor(s, o, 64);
    const float m = s * (1.0f / 512.0f);
    float s2 = 0.f;
    #pragma unroll
    for (int j = 0; j < 8; ++j){ const float d = x[j] - m; s2 = fmaf(d, d, s2); }
    for (int o = 32; o; o >>= 1) s2 += __shfl_xor(s2, o, 64);
    const float inv = 1.0f / sqrtf(s2 * (1.0f / 512.0f) + 1e-5f);
    #pragma unroll
    for (int j = 0; j < 8; ++j){
      const int c = lane + (j << 6);
      const float r = (x[j] - m) * inv * ln_g[c] + ln_b[c];
      const size_t o2 = gp * DIMV + c;
      if (WRITE_EMB) emb[o2] = f2bf(x[j]);
      lnout[o2] = f2bf(r);
    }
  }
}

template<bool GATHER, bool WRITE_EMB>
__global__ __launch_bounds__(256) void embed_kernel(
    const float* __restrict__ pc, const float* __restrict__ pc2,
    const int* __restrict__ idx,
    const float* __restrict__ basis, const float* __restrict__ pe_w,
    const float* __restrict__ pe_b,
    const float* __restrict__ ln_g, const float* __restrict__ ln_b,
    bfu* __restrict__ emb, bfu* __restrict__ lnout, int nppbt)
{
  __shared__ float feat[2][16][NFEAT + 1];
  __shared__ float outb[16][DIMV];
  embed_body<GATHER, WRITE_EMB>(blockIdx.x, threadIdx.x, pc, pc2, idx, basis,
      pe_w, pe_b, ln_g, ln_b, emb, lnout, nppbt, feat, outb);
}

// ---------------------------------------------------------------------------
// Transpose body (weights only): in [R][C] fp32 -> out bf16 [C][R].
// ---------------------------------------------------------------------------
template<typename TIN>
__device__ __forceinline__ void transp_body(
    const TIN* __restrict__ in, bfu* __restrict__ out, int R, int C,
    int bx, int by, bfu (*t)[33])
{
  const int c0 = bx * 32, r0 = by * 32;
  const int tx = threadIdx.x & 31, ty = threadIdx.x >> 5;
  #pragma unroll
  for (int rr = ty; rr < 32; rr += 8)
    t[rr][tx] = to_bfu(in[(size_t)(r0 + rr) * C + c0 + tx]);
  __syncthreads();
  #pragma unroll
  for (int rr = ty; rr < 32; rr += 8)
    out[(size_t)(c0 + rr) * R + r0 + tx] = t[tx][rr];
}

// ---------------------------------------------------------------------------
// fused_pre: one launch hiding FPS-independent work under FPS's shadow.
// Blocks [0,16): FPS. [16,784): context embed group 0 -> c_grp.
// [784,4880): the 5 weight transposes.
// ---------------------------------------------------------------------------
__global__ __attribute__((amdgpu_waves_per_eu(1, 1)))
__launch_bounds__(256) void fused_pre(
    const float* __restrict__ pc, const float* __restrict__ pc2,
    int* __restrict__ idx_out,
    const float* __restrict__ basis, const float* __restrict__ pe_w,
    const float* __restrict__ pe_b,
    const float* __restrict__ lnc_g, const float* __restrict__ lnc_b,
    bfu* __restrict__ c_grp,
    const float* __restrict__ wq, const float* __restrict__ wkv,
    const float* __restrict__ wo, const float* __restrict__ w1,
    const float* __restrict__ w2,
    bfu* __restrict__ wqT, bfu* __restrict__ wkvT, bfu* __restrict__ woT,
    bfu* __restrict__ w1T, bfu* __restrict__ w2T)
{
  __shared__ __align__(16) char smem[39424];  // max(fps 192, embed 39424, transp 2112)
  const int bid = blockIdx.x, tid = threadIdx.x;

  if (bid < NB){
    #pragma clang fp contract(off)
    float4 (*xyz)[4] = (float4(*)[4])smem;            // 2*4*16 = 128 B
    int2   (*vi)[4]  = (int2(*)[4])(smem + 128);      // 2*4*8  = 64 B
    fps_body(bid, tid, pc, idx_out, xyz, vi);
    return;
  }
  const int rb = bid - NB;
  if (rb < GROWS / 16){
    embed_body<false, false>(rb, tid, pc, pc2, nullptr, basis, pe_w, pe_b,
                             lnc_g, lnc_b, nullptr, c_grp, NCTX,
                             (float(*)[16][NFEAT + 1])smem,
                             (float(*)[DIMV])(smem + 6656));
    return;
  }
  int tb = rb - GROWS / 16;
  bfu (*tile)[33] = (bfu(*)[33])smem;
  if (tb < 256){ transp_body<float>(wq,  wqT,  512,  512, tb & 15,  tb >> 4, tile); return; }
  tb -= 256;
  if (tb < 512){ transp_body<float>(wkv, wkvT, 512, 1024, tb & 31,  tb >> 5, tile); return; }
  tb -= 512;
  if (tb < 256){ transp_body<float>(wo,  woT,  512,  512, tb & 15,  tb >> 4, tile); return; }
  tb -= 256;
  if (tb < 2048){ transp_body<float>(w1, w1T,  512, 4096, tb & 127, tb >> 7, tile); return; }
  tb -= 2048;
  transp_body<float>(w2, w2T, 2048, 512, tb & 15, tb >> 4, tile);
}

// ---------------------------------------------------------------------------
// MFMA GEMM: C[M][N] = A[M][K] * B[N][K]^T, bf16 inputs.
// Tile = (FH*32)^2: FH=4 -> 128x128, FH=2 -> 64x64. 4 waves 2x2.
// global_load_lds width=16 staging (R6) + KSTEP-deep barrier amortization
// (R7). LDS linear [BT][KSTEP]; 2-way-max bank conflicts via XOR chunk
// swizzle (inverse on per-lane GLOBAL source + same XOR on ds_read).
// ---------------------------------------------------------------------------
#define EPI_NONE     0
#define EPI_SPLIT    1
#define EPI_SCALE    2
#define EPI_BIAS_RES 3

template<int FH, int KSTEP, typename TC, typename TR, int EPI>
__global__ __launch_bounds__(256, 2) void gemm_mfma(
    const bfu* __restrict__ A, const bfu* __restrict__ B,
    TC* __restrict__ C, TC* __restrict__ C2,
    const float* __restrict__ bias, const TR* __restrict__ res,
    float scale, int N, int K, int lda, int ldb, int ldc,
    long long sA, long long sB, long long sC)
{
  constexpr int BT  = FH * 32;             // block tile edge
  constexpr int CPR = KSTEP / 8;           // 16B chunks per row
  constexpr int NI  = (BT * CPR) / 256;    // chunk issues per wave per matrix
  const int bz = blockIdx.z;
  A += (size_t)bz * sA;
  B += (size_t)bz * sB;
  const size_t coff = (size_t)bz * sC;

  __shared__ __align__(16) short As[BT * KSTEP];
  __shared__ __align__(16) short Bs[BT * KSTEP];

  const int tid = threadIdx.x;
  const int lane = tid & 63, w = tid >> 6;
  const int wl = (w << 6) + lane;
  const int m0 = blockIdx.y * BT, n0 = blockIdx.x * BT;
  const int wm = (w & 1) * (FH * 16), wn = (w >> 1) * (FH * 16);
  const int fr = lane & 15, quad = lane >> 4;

  f32x4 acc[FH][FH];
  #pragma unroll
  for (int i = 0; i < FH; ++i)
    #pragma unroll
    for (int j = 0; j < FH; ++j)
      #pragma unroll
      for (int r = 0; r < 4; ++r) acc[i][j][r] = 0.f;

  for (int k0 = 0; k0 < K; k0 += KSTEP){
    #pragma unroll
    for (int i = 0; i < NI; ++i){
      const int ch = i * 256 + wl;         // stored chunk: row r, slot cs
      const int r  = ch / CPR, cs = ch & (CPR - 1);
      const int cg = cs ^ swzr<KSTEP>(r);  // global chunk (inverse swizzle)
      short* la = (short*)As + ((i * 256 + (w << 6)) << 3); // wave-uniform
      short* lb = (short*)Bs + ((i * 256 + (w << 6)) << 3);
      GLD16(A + (size_t)(m0 + r) * lda + k0 + cg * 8, la);
      GLD16(B + (size_t)(n0 + r) * ldb + k0 + cg * 8, lb);
    }
    __syncthreads();
    #pragma unroll
    for (int kk = 0; kk < KSTEP / 32; ++kk){
      bf16x8 af[FH], bf[FH];
      #pragma unroll
      for (int i = 0; i < FH; ++i){
        const int row = wm + i * 16 + fr;
        const int cl = (kk * 4 + quad) ^ swzr<KSTEP>(row);
        af[i] = *(const bf16x8*)&As[row * KSTEP + (cl << 3)];
      }
      #pragma unroll
      for (int j = 0; j < FH; ++j){
        const int row = wn + j * 16 + fr;
        const int cl = (kk * 4 + quad) ^ swzr<KSTEP>(row);
        bf[j] = *(const bf16x8*)&Bs[row * KSTEP + (cl << 3)];
      }
      #pragma unroll
      for (int i = 0; i < FH; ++i)
        #pragma unroll
        for (int j = 0; j < FH; ++j)
          acc[i][j] = __builtin_amdgcn_mfma_f32_16x16x32_bf16(af[i], bf[j], acc[i][j], 0, 0, 0);
    }
    __syncthreads();
  }

  // C/D layout: col = lane&15, row = quad*4 + reg
  TC* Cp = C + coff;
  #pragma unroll
  for (int i = 0; i < FH; ++i){
    #pragma unroll
    for (int r = 0; r < 4; ++r){
      const int cm = m0 + wm + i * 16 + quad * 4 + r;
      #pragma unroll
      for (int j = 0; j < FH; ++j){
        const int cn = n0 + wn + j * 16 + fr;
        float v = acc[i][j][r];
        if (EPI == EPI_SCALE)    v *= scale;
        if (EPI == EPI_BIAS_RES) v = v + bias[cn] + loadE(&res[coff + (size_t)cm * ldc + cn]);
        if (EPI == EPI_SPLIT){
          const int half = N >> 1;
          if (cn < half) storeE(&C [(size_t)cm * half + cn],          v);
          else           storeE(&C2[(size_t)cm * half + (cn - half)], v);
        } else {
          storeE(&Cp[(size_t)cm * ldc + cn], v);
        }
      }
    }
  }
}

// ---------------------------------------------------------------------------
// kv_mfma: fused same-shape GEMM launch (all FH=4, KSTEP=64, EPI_NONE,
// bf16 out, K=512, lda=ldb=512). Linear block decode:
//   [0, nq):        q  = q_in @ wqT    (nq = 768 for group 0, else 0)
//   [nq, nq+384):   k  = c   @ wkT     (wkvT rows 0..511)
//   [nq+384, +768): vT = wvT @ cT      (64 blocks per bt, 6 bt)
// R10: -1 launch per group (+q for g0), better CU fill, shared c_grp L2
// locality. Outputs disjoint; inputs read-only -> race-free.
// ---------------------------------------------------------------------------
__global__ __launch_bounds__(256, 2) void kv_mfma(
    int nq,
    const bfu* __restrict__ qA, const bfu* __restrict__ qB, bfu* __restrict__ qC,
    const bfu* __restrict__ cg, const bfu* __restrict__ wkvT,
    bfu* __restrict__ kg, bfu* __restrict__ vg)
{
  constexpr int KSTEP = 64, CPR = 8, NI = 4;
  const bfu *A, *B; bfu *C; int m0, n0, ldc;
  {
    int bid = blockIdx.x;
    if (bid < nq){
      A = qA; B = qB; C = qC;
      m0 = (bid >> 2) * 128; n0 = (bid & 3) * 128; ldc = 512;
    } else {
      bid -= nq;
      if (bid < 384){
        A = cg; B = wkvT; C = kg;
        m0 = (bid >> 2) * 128; n0 = (bid & 3) * 128; ldc = 512;
      } else {
        const int r = bid - 384, z = r >> 6, rr = r & 63;
        A = wkvT + 512 * 512;
        B = cg + (size_t)z * 1048576;
        C = vg + (size_t)z * 1048576;
        m0 = (rr >> 4) * 128; n0 = (rr & 15) * 128; ldc = 2048;
      }
    }
  }

  __shared__ __align__(16) short As[128 * KSTEP];
  __shared__ __align__(16) short Bs[128 * KSTEP];

  const int tid = threadIdx.x;
  const int lane = tid & 63, w = tid >> 6;
  const int wl = (w << 6) + lane;
  const int wm = (w & 1) * 64, wn = (w >> 1) * 64;
  const int fr = lane & 15, quad = lane >> 4;

  f32x4 acc[4][4];
  #pragma unroll
  for (int i = 0; i < 4; ++i)
    #pragma unroll
    for (int j = 0; j < 4; ++j)
      #pragma unroll
      for (int r = 0; r < 4; ++r) acc[i][j][r] = 0.f;

  for (int k0 = 0; k0 < 512; k0 += KSTEP){
    #pragma unroll
    for (int i = 0; i < NI; ++i){
      const int ch = i * 256 + wl;
      const int r  = ch / CPR, cs = ch & (CPR - 1);
      const int cg2 = cs ^ swzr<KSTEP>(r);
      short* la = (short*)As + ((i * 256 + (w << 6)) << 3);
      short* lb = (short*)Bs + ((i * 256 + (w << 6)) << 3);
      GLD16(A + (size_t)(m0 + r) * 512 + k0 + cg2 * 8, la);
      GLD16(B + (size_t)(n0 + r) * 512 + k0 + cg2 * 8, lb);
    }
    __syncthreads();
    #pragma unroll
    for (int kk = 0; kk < KSTEP / 32; ++kk){
      bf16x8 af[4], bf[4];
      #pragma unroll
      for (int i = 0; i < 4; ++i){
        const int row = wm + i * 16 + fr;
        const int cl = (kk * 4 + quad) ^ swzr<KSTEP>(row);
        af[i] = *(const bf16x8*)&As[row * KSTEP + (cl << 3)];
      }
      #pragma unroll
      for (int j = 0; j < 4; ++j){
        const int row = wn + j * 16 + fr;
        const int cl = (kk * 4 + quad) ^ swzr<KSTEP>(row);
        bf[j] = *(const bf16x8*)&Bs[row * KSTEP + (cl << 3)];
      }
      #pragma unroll
      for (int i = 0; i < 4; ++i)
        #pragma unroll
        for (int j = 0; j < 4; ++j)
          acc[i][j] = __builtin_amdgcn_mfma_f32_16x16x32_bf16(af[i], bf[j], acc[i][j], 0, 0, 0);
    }
    __syncthreads();
  }

  #pragma unroll
  for (int i = 0; i < 4; ++i){
    #pragma unroll
    for (int r = 0; r < 4; ++r){
      const int cm = m0 + wm + i * 16 + quad * 4 + r;
      #pragma unroll
      for (int j = 0; j < 4; ++j){
        const int cn = n0 + wn + j * 16 + fr;
        C[(size_t)cm * ldc + cn] = f2bf(acc[i][j][r]);
      }
    }
  }
}

// ---------------------------------------------------------------------------
// Fused MLP1 + exact GeLU (MFMA): act = (A@w1T[a]+b1a) * gelu(A@w1T[g]+b1g).
// Same global_load_lds + XOR-swizzle staging, KSTEP=64.
// ---------------------------------------------------------------------------
__global__ __launch_bounds__(256, 1) void mlp1_mfma(
    const bfu* __restrict__ A, const bfu* __restrict__ B,  // B = w1T [4096][512]
    const float* __restrict__ b1, bfu* __restrict__ act)
{
  constexpr int KSTEP = 64, CPR = 8, NI = 4;
  __shared__ __align__(16) short As[128 * KSTEP];
  __shared__ __align__(16) short Ba[128 * KSTEP];
  __shared__ __align__(16) short Bg[128 * KSTEP];

  const int tid = threadIdx.x;
  const int lane = tid & 63, w = tid >> 6;
  const int wl = (w << 6) + lane;
  const int m0 = blockIdx.y * 128, n0 = blockIdx.x * 128;
  const int wm = (w & 1) * 64, wn = (w >> 1) * 64;
  const int fr = lane & 15, quad = lane >> 4;

  f32x4 acca[4][4], accg[4][4];
  #pragma unroll
  for (int i = 0; i < 4; ++i)
    #pragma unroll
    for (int j = 0; j < 4; ++j)
      #pragma unroll
      for (int r = 0; r < 4; ++r){ acca[i][j][r] = 0.f; accg[i][j][r] = 0.f; }

  for (int k0 = 0; k0 < 512; k0 += KSTEP){
    #pragma unroll
    for (int i = 0; i < NI; ++i){
      const int ch = i * 256 + wl;
      const int r  = ch / CPR, cs = ch & (CPR - 1);
      const int cg = cs ^ swzr<KSTEP>(r);
      short* da = (short*)As + ((i * 256 + (w << 6)) << 3);
      short* db = (short*)Ba + ((i * 256 + (w << 6)) << 3);
      short* dg = (short*)Bg + ((i * 256 + (w << 6)) << 3);
      GLD16(A + (size_t)(m0 + r) * 512 + k0 + cg * 8, da);
      GLD16(B + (size_t)(n0 + r) * 512 + k0 + cg * 8, db);
      GLD16(B + (size_t)(n0 + 2048 + r) * 512 + k0 + cg * 8, dg);
    }
    __syncthreads();
    #pragma unroll
    for (int kk = 0; kk < KSTEP / 32; ++kk){
      bf16x8 af[4], ba[4], bg[4];
      #pragma unroll
      for (int i = 0; i < 4; ++i){
        const int row = wm + i * 16 + fr;
        const int cl = (kk * 4 + quad) ^ swzr<KSTEP>(row);
        af[i] = *(const bf16x8*)&As[row * KSTEP + (cl << 3)];
      }
      #pragma unroll
      for (int j = 0; j < 4; ++j){
        const int row = wn + j * 16 + fr;
        const int cl = (kk * 4 + quad) ^ swzr<KSTEP>(row);
        ba[j] = *(const bf16x8*)&Ba[row * KSTEP + (cl << 3)];
        bg[j] = *(const bf16x8*)&Bg[row * KSTEP + (cl << 3)];
      }
      #pragma unroll
      for (int i = 0; i < 4; ++i)
        #pragma unroll
        for (int j = 0; j < 4; ++j){
          acca[i][j] = __builtin_amdgcn_mfma_f32_16x16x32_bf16(af[i], ba[j], acca[i][j], 0, 0, 0);
          accg[i][j] = __builtin_amdgcn_mfma_f32_16x16x32_bf16(af[i], bg[j], accg[i][j], 0, 0, 0);
        }
    }
    __syncthreads();
  }

  #pragma unroll
  for (int i = 0; i < 4; ++i){
    #pragma unroll
    for (int r = 0; r < 4; ++r){
      const int cm = m0 + wm + i * 16 + quad * 4 + r;
      #pragma unroll
      for (int j = 0; j < 4; ++j){
        const int cn = n0 + wn + j * 16 + fr;
        const float a = acca[i][j][r] + b1[cn];
        const float g = accg[i][j][r] + b1[cn + 2048];
        const float ge = g * 0.5f * (1.0f + erff(g * 0.70710678118654752f));
        act[(size_t)cm * 2048 + cn] = f2bf(a * ge);
      }
    }
  }
}

// ---------------------------------------------------------------------------
// Row softmax over 2048 bf16 logits, in place.
// ---------------------------------------------------------------------------
__global__ __launch_bounds__(256) void softmax_kernel(bfu* __restrict__ sc){
  __shared__ float red[4];
  const int tid = threadIdx.x;
  const int lane = tid & 63, wv = tid >> 6;
  bfu* rp = sc + (size_t)blockIdx.x * NCTX;
  float x[8];
  #pragma unroll
  for (int j = 0; j < 8; ++j) x[j] = bf2f(rp[tid + (j << 8)]);
  float mx = x[0];
  #pragma unroll
  for (int j = 1; j < 8; ++j) mx = fmaxf(mx, x[j]);
  for (int o = 32; o; o >>= 1) mx = fmaxf(mx, __shfl_xor(mx, o, 64));
  if (lane == 0) red[wv] = mx;
  __syncthreads();
  mx = fmaxf(fmaxf(red[0], red[1]), fmaxf(red[2], red[3]));
  float sum = 0.f;
  #pragma unroll
  for (int j = 0; j < 8; ++j){ x[j] = __expf(x[j] - mx); sum += x[j]; }
  for (int o = 32; o; o >>= 1) sum += __shfl_xor(sum, o, 64);
  __syncthreads();
  if (lane == 0) red[wv] = sum;
  __syncthreads();
  sum = red[0] + red[1] + red[2] + red[3];
  const float inv = 1.0f / sum;
  #pragma unroll
  for (int j = 0; j < 8; ++j) rp[tid + (j << 8)] = f2bf(x[j] * inv);
}

// ---------------------------------------------------------------------------
// LayerNorm rows of 512 fp32 -> bf16.
// ---------------------------------------------------------------------------
__global__ __launch_bounds__(256) void ln_kernel(const float* __restrict__ in,
                                                 const float* __restrict__ g,
                                                 const float* __restrict__ b,
                                                 bfu* __restrict__ out){
  const int tid = threadIdx.x, lane = tid & 63, wv = tid >> 6;
  const size_t row = (size_t)blockIdx.x * 4 + wv;
  const float* rp = in + row * DIMV;
  float x[8];
  #pragma unroll
  for (int j = 0; j < 8; ++j) x[j] = rp[lane + (j << 6)];
  float s = 0.f;
  #pragma unroll
  for (int j = 0; j < 8; ++j) s += x[j];
  for (int o = 32; o; o >>= 1) s += __shfl_xor(s, o, 64);
  const float m = s * (1.0f / 512.0f);
  float s2 = 0.f;
  #pragma unroll
  for (int j = 0; j < 8; ++j){ const float d = x[j] - m; s2 = fmaf(d, d, s2); }
  for (int o = 32; o; o >>= 1) s2 += __shfl_xor(s2, o, 64);
  const float inv = 1.0f / sqrtf(s2 * (1.0f / 512.0f) + 1e-5f);
  bfu* op = out + row * DIMV;
  #pragma unroll
  for (int j = 0; j < 8; ++j){
    const int c = lane + (j << 6);
    op[c] = f2bf((x[j] - m) * inv * g[c] + b[c]);
  }
}

// ---------------------------------------------------------------------------
// Workspace (peak 121,667,584 B < proven 125,861,888):
//   idx    @ 0          (32 KB)
//   emb_s  @ 32768      (25,165,824) \  act half (50,331,648) aliases
//   q_in   @ 25198592   (25,165,824) /  emb_s+q_in (both dead at MLP)
//          q_in -> attnout after q GEMM
//   c_grp  @ 50364416   (12,582,912) -> scores (GRP=6)
//   k_grp  @ 62947328   (12,582,912)
//   v_grp  @ 75530240   (12,582,912) = vT directly (R9: kv split, no transp)
//   qbuf   @ 88113152   (25,165,824) -> lnx
//   wT     @ 113278976  (8,388,608): wqT|wkvT|woT|w1T|w2T
// ---------------------------------------------------------------------------
extern "C" void kernel_launch(void* const* d_in, const int* in_sizes, int n_in,
                              void* d_out, int out_size, void* d_ws, size_t ws_size,
                              hipStream_t stream)
{
  (void)in_sizes; (void)n_in; (void)out_size;
  if (ws_size < 121667584ull) return;

  const float* pc    = (const float*)d_in[0];
  const float* pc2   = (const float*)d_in[1];
  const float* basis = (const float*)d_in[2];
  const float* pe_w  = (const float*)d_in[3];
  const float* pe_b  = (const float*)d_in[4];
  const float* lnq_g = (const float*)d_in[5];
  const float* lnq_b = (const float*)d_in[6];
  const float* lnc_g = (const float*)d_in[7];
  const float* lnc_b = (const float*)d_in[8];
  const float* wq    = (const float*)d_in[9];
  const float* wkv   = (const float*)d_in[10];
  const float* wo    = (const float*)d_in[11];
  const float* bo    = (const float*)d_in[12];
  const float* lnf_g = (const float*)d_in[13];
  const float* lnf_b = (const float*)d_in[14];
  const float* w1    = (const float*)d_in[15];
  const float* b1    = (const float*)d_in[16];
  const float* w2    = (const float*)d_in[17];
  const float* b2    = (const float*)d_in[18];
  float* xout = (float*)d_out;

  char* ws = (char*)d_ws;
  int* idxb   = (int*)(ws);
  bfu* emb_s  = (bfu*)(ws + 32768);
  bfu* q_in   = (bfu*)(ws + 25198592);
  bfu* c_grp  = (bfu*)(ws + 50364416);
  bfu* k_grp  = (bfu*)(ws + 62947328);
  bfu* v_grp  = (bfu*)(ws + 75530240);
  bfu* qbuf   = (bfu*)(ws + 88113152);
  bfu* wqT    = (bfu*)(ws + 113278976);
  bfu* wkvT   = (bfu*)(ws + 113803264);
  bfu* woT    = (bfu*)(ws + 114851840);
  bfu* w1T    = (bfu*)(ws + 115376128);
  bfu* w2T    = (bfu*)(ws + 119570432);
  bfu* scores  = c_grp;     // after c consumed by k/vT GEMMs
  bfu* vT      = v_grp;     // written transposed directly
  bfu* attnout = q_in;      // after q GEMM consumed q_in
  bfu* lnx     = qbuf;      // after attention consumed q
  bfu* actb    = emb_s;     // spans emb_s+q_in (one MLP half at a time)

  // 0+1. fused: FPS || {weight transposes, group-0 context embed}
  fused_pre<<<FUSED_BLKS, 256, 0, stream>>>(
      pc, pc2, idxb, basis, pe_w, pe_b, lnc_g, lnc_b, c_grp,
      wq, wkv, wo, w1, w2, wqT, wkvT, woT, w1T, w2T);

  // 2. latent embed -> emb_s (raw) + q_in (LN'd)   [needs idxb]
  embed_kernel<true, true><<<MROWS/16, 256, 0, stream>>>(
      pc, pc2, idxb, basis, pe_w, pe_b, lnq_g, lnq_b, emb_s, q_in, NLAT);

  // 3/4. per-group context pipeline (GRP=6, 8 groups; g0 embed done in
  // fused_pre; q GEMM fused into g0's kv launch)
  for (int g = 0; g < NGRP; ++g){
    const int bt0 = g * GRP;
    if (g > 0){
      embed_kernel<false, false><<<GROWS/16, 256, 0, stream>>>(
          pc + (size_t)bt0 * NCTX * 3, pc2 + (size_t)bt0 * NCTX * 3, nullptr,
          basis, pe_w, pe_b, lnc_g, lnc_b, nullptr, c_grp, NCTX);
    }

    // fused {q (g0 only)} + {k = c @ wkT} + {vT = wvT @ cT}
    const int nq = (g == 0) ? 768 : 0;
    kv_mfma<<<nq + 768, 256, 0, stream>>>(
        nq, q_in, wqT, qbuf, c_grp, wkvT, k_grp, v_grp);

    // scores = (q @ k^T) * scale (overwrites c_grp region)
    gemm_mfma<4, 64, bfu, float, EPI_SCALE><<<dim3(16, 4, GRP), 256, 0, stream>>>(
        qbuf + (size_t)bt0 * 262144, k_grp, scores, nullptr, nullptr, nullptr,
        0.044194173824159216f,
        2048, 512, 512, 512, 2048, 262144, 1048576, 1048576);

    softmax_kernel<<<GRP * 512, 256, 0, stream>>>(scores);

    // attnout = P @ V : 64x64 tiles, KSTEP=128
    gemm_mfma<2, 128, bfu, float, EPI_NONE><<<dim3(8, 8, GRP), 256, 0, stream>>>(
        scores, vT, attnout + (size_t)bt0 * 262144, nullptr, nullptr, nullptr, 1.0f,
        512, 2048, 2048, 2048, 512, 1048576, 1048576, 262144);
  }

  // 5. x = attnout @ wo + bo + emb_s -> d_out (fp32)
  gemm_mfma<4, 64, float, bfu, EPI_BIAS_RES><<<dim3(4, 192, 1), 256, 0, stream>>>(
      attnout, woT, xout, nullptr, bo, emb_s, 1.0f,
      512, 512, 512, 512, 512, 0, 0, 0);

  // 6. lnx = LN(x)
  ln_kernel<<<MROWS/4, 256, 0, stream>>>(xout, lnf_g, lnf_b, lnx);

  // 7/8. MLP in two row-halves (act buffer holds one half)
  for (int h = 0; h < 2; ++h){
    const size_t ro = (size_t)h * 12288;
    mlp1_mfma<<<dim3(16, 96, 1), 256, 0, stream>>>(
        lnx + ro * 512, w1T, b1, actb);
    gemm_mfma<4, 64, float, float, EPI_BIAS_RES><<<dim3(4, 96, 1), 256, 0, stream>>>(
        actb, w2T, xout + ro * 512, nullptr, b2, xout + ro * 512, 1.0f,
        512, 2048, 2048, 2048, 512, 0, 0, 0);
  }
}

// Round 12
// 1494.237 us; speedup vs baseline: 1.1057x; 1.1057x over previous
//
#include <hip/hip_runtime.h>

// Problem constants
#define NB    16
#define NT    3
#define NCTX  2048
#define NLAT  512
#define DIMV  512
#define HALFD 256
#define NFEAT 51
#define NBT   48
#define MROWS 24576    // NBT*NLAT
#define GRP   6        // bt per context group
#define NGRP  8
#define GROWS 12288    // GRP*NCTX
#define FUSED_BLKS (NB + GROWS/16 + 4096)   // fps + g0 embed + 5 transposes

typedef unsigned short bfu;   // bf16 storage as raw bits
typedef short bf16x8 __attribute__((ext_vector_type(8)));   // 8 bf16 = 4 VGPR
typedef float f32x4  __attribute__((ext_vector_type(4)));   // MFMA 16x16 acc
typedef float f32x2  __attribute__((ext_vector_type(2)));   // packed fp32 pair

__device__ __forceinline__ float bf2f(bfu u){ return __uint_as_float(((unsigned int)u) << 16); }
__device__ __forceinline__ bfu f2bf(float f){
  unsigned int u = __float_as_uint(f);
  u += 0x7FFFu + ((u >> 16) & 1u);          // RNE
  return (bfu)(u >> 16);
}
__device__ __forceinline__ float loadE(const float* p){ return *p; }
__device__ __forceinline__ float loadE(const bfu* p){ return bf2f(*p); }
__device__ __forceinline__ void storeE(float* p, float v){ *p = v; }
__device__ __forceinline__ void storeE(bfu* p, float v){ *p = f2bf(v); }
__device__ __forceinline__ bfu to_bfu(float f){ return f2bf(f); }
__device__ __forceinline__ bfu to_bfu(bfu u){ return u; }

// Async 16B global->LDS DMA. LDS dest = wave-uniform base + lane*16 (linear!)
// so swizzled layouts are achieved by pre-swizzling the per-lane GLOBAL
// source address (m173 pattern), never the LDS dest.
#define GLD16(gp, lp) __builtin_amdgcn_global_load_lds(                       \
    (const __attribute__((address_space(1))) unsigned int*)(gp),              \
    (__attribute__((address_space(3))) unsigned int*)(lp), 16, 0, 0)

// XOR chunk swizzle key for a [*][KSTEP] bf16 LDS tile (16B chunks).
template<int KSTEP>
__device__ __forceinline__ int swzr(int r){
  constexpr int CPR = KSTEP / 8;
  return (KSTEP == 32) ? ((r >> 1) & 3) : (r & (CPR - 1));
}

// ---------------------------------------------------------------------------
// FPS core: FOUR waves per batch, 512 pts/wave register-resident (R10's
// proven 322us configuration, restored verbatim after R11's coords-in-record
// variant regressed to 467us -- lesson: the per-step cost is DEPENDENCY
// DEPTH, not load count; replacing one pipelined uniform ds_read_b128 with
// a DPP-dependent 21-cndmask select tree + extra LDS write + 8-load merge
// lengthened the serial chain by ~680cy/step).
// Per step: pts[last] broadcast -> packed VALU dist update -> in-lane tree
// (8 slots) -> 6-stage DPP wave argmax -> lane-63 8B record, ONE barrier
// (parity dbuf), 32B merge read, sequential strict-> select.
// Tie-breaks preserve numpy first-max exactly: index-ordered in-lane merges,
// DPP carries global idx (tie -> lower), wave ranges ascending so strict >
// keeps the lowest index. Distance expression, fminf, 1e10f identical to
// the proven bit-exact version (contract(off) at the caller).
// ---------------------------------------------------------------------------
#define DPP_ARGMAX_STAGE(CTRL)                                                \
  {                                                                           \
    const int svb = __builtin_amdgcn_update_dpp(vb, vb, CTRL, 0xF, 0xF, false); \
    const int sib = __builtin_amdgcn_update_dpp(ib, ib, CTRL, 0xF, 0xF, false); \
    const float sv = __int_as_float(svb);                                     \
    const float cv = __int_as_float(vb);                                      \
    if (sv > cv || (sv == cv && sib < ib)){ vb = svb; ib = sib; }             \
  }

__device__ __forceinline__ void fps_body(int b, int tid, const float* __restrict__ pc,
                                         int* __restrict__ idx_out,
                                         float4* pts, int (*mbuf)[8]){
  const int lane = tid & 63, w = tid >> 6;
  const int wbase = w << 9;               // wave owns [512w, 512w+512)
  const float* src = pc + (size_t)b * (NT * NCTX * 3);

  // Slot s (0..7) = point p = wbase + (s<<6) + lane. Coords + running
  // min-dists all register-resident; pair j holds slots 2j (lo), 2j+1 (hi).
  f32x2 x2[4], y2[4], z2[4], d2[4];
  #pragma unroll
  for (int j = 0; j < 4; ++j){
    #pragma unroll
    for (int h = 0; h < 2; ++h){
      const int p = wbase + ((2 * j + h) << 6) + lane;
      const float xx = src[p * 3 + 0];
      const float yy = src[p * 3 + 1];
      const float zz = src[p * 3 + 2];
      x2[j][h] = xx; y2[j][h] = yy; z2[j][h] = zz;
      pts[p] = make_float4(xx, yy, zz, 0.f);
    }
    d2[j][0] = 1e10f; d2[j][1] = 1e10f;
  }
  if (tid == 0) idx_out[b * NLAT] = 0;
  __syncthreads();                        // pts table ready

  int last = 0;
  for (int step = 1; step < NLAT; ++step){
    const float4 lp = pts[last];          // uniform addr -> LDS broadcast

    // distance update: pure packed VALU, identical op order to the proven
    // bit-exact version.
    #pragma unroll
    for (int j = 0; j < 4; ++j){
      const f32x2 dx = x2[j] - lp.x;
      const f32x2 dy = y2[j] - lp.y;
      const f32x2 dz = z2[j] - lp.z;
      const f32x2 dd = (dx * dx + dy * dy) + dz * dz;
      f32x2 nd;
      nd[0] = fminf(d2[j][0], dd[0]);
      nd[1] = fminf(d2[j][1], dd[1]);
      d2[j] = nd;
    }

    // in-lane argmax over 8 slots, adjacent-pair tree (index-ordered
    // merges: strict > keeps the lowest index on ties).
    float av[4]; int as_[4];
    #pragma unroll
    for (int j = 0; j < 4; ++j){
      const float lo = d2[j][0], hi = d2[j][1];
      const bool t = hi > lo;
      av[j]  = t ? hi : lo;
      as_[j] = t ? 2 * j + 1 : 2 * j;
    }
    #pragma unroll
    for (int wdt = 2; wdt; wdt >>= 1){
      #pragma unroll
      for (int j = 0; j < wdt; ++j){
        const float lv = av[2 * j], rv = av[2 * j + 1];
        const int   li = as_[2 * j], ri = as_[2 * j + 1];
        const bool t = rv > lv;
        av[j]  = t ? rv : lv;
        as_[j] = t ? ri : li;
      }
    }

    // cross-lane argmax on (value, GLOBAL index); ties -> lower index
    int vb = __float_as_int(av[0]);
    int ib = wbase + (as_[0] << 6) + lane;
    DPP_ARGMAX_STAGE(0x111)   // row_shr:1
    DPP_ARGMAX_STAGE(0x112)   // row_shr:2
    DPP_ARGMAX_STAGE(0x114)   // row_shr:4
    DPP_ARGMAX_STAGE(0x118)   // row_shr:8
    DPP_ARGMAX_STAGE(0x142)   // row_bcast:15
    DPP_ARGMAX_STAGE(0x143)   // row_bcast:31

    // cross-wave merge: 8B record (lane 63), one barrier, 32B broadcast
    // read, sequential strict-> select (wave ranges ascending -> numpy
    // tie-break). Parity buffer -> no second barrier.
    const int par = step & 1;
    if (lane == 63){ mbuf[par][w * 2] = vb; mbuf[par][w * 2 + 1] = ib; }
    __syncthreads();
    const int4 q0 = *(const int4*)&mbuf[par][0];
    const int4 q1 = *(const int4*)&mbuf[par][4];
    float bv = __int_as_float(q0.x); int bi = q0.y;
    { const float v1 = __int_as_float(q0.z); if (v1 > bv){ bv = v1; bi = q0.w; } }
    { const float v2 = __int_as_float(q1.x); if (v2 > bv){ bv = v2; bi = q1.y; } }
    { const float v3 = __int_as_float(q1.z); if (v3 > bv){ bv = v3; bi = q1.w; } }
    last = bi;
    if (tid == 0) idx_out[b * NLAT + step] = last;
  }
}

// ---------------------------------------------------------------------------
// Embed body: gather + point_embed x2 + layernorm -> bf16. 16 points/block.
// Phase-1 trig parallelized over all 256 threads (bit-exact redistribution).
// ---------------------------------------------------------------------------
template<bool GATHER, bool WRITE_EMB>
__device__ __forceinline__ void embed_body(
    int bid, int tid,
    const float* __restrict__ pc, const float* __restrict__ pc2,
    const int* __restrict__ idx,
    const float* __restrict__ basis, const float* __restrict__ pe_w,
    const float* __restrict__ pe_b,
    const float* __restrict__ ln_g, const float* __restrict__ ln_b,
    bfu* __restrict__ emb, bfu* __restrict__ lnout, int nppbt,
    float (*feat)[16][NFEAT + 1], float (*outb)[DIMV])
{
  const int p0 = bid << 4;

  if (tid < 32){
    const int s = tid >> 4, p = tid & 15;
    const int gp = p0 + p;
    const int bt = gp / nppbt;
    const int n  = gp - bt * nppbt;
    const int bb = bt / NT;
    const int srcn = GATHER ? idx[bb * NLAT + n] : n;
    const float* sp = (s ? pc2 : pc) + ((size_t)bt * NCTX + srcn) * 3;
    feat[s][p][48] = sp[0]; feat[s][p][49] = sp[1]; feat[s][p][50] = sp[2];
  }
  __syncthreads();

  #pragma unroll
  for (int t = 0; t < 3; ++t){
    const int wk  = tid * 3 + t;          // [0,768): (s*16+p)*24 + e
    const int spq = wk / 24;
    const int e   = wk - spq * 24;
    const int s = spq >> 4, p = spq & 15;
    const float x0 = feat[s][p][48], x1 = feat[s][p][49], x2 = feat[s][p][50];
    const float pr = __fadd_rn(__fadd_rn(__fmul_rn(x0, basis[e]),
                                         __fmul_rn(x1, basis[24 + e])),
                               __fmul_rn(x2, basis[48 + e]));
    feat[s][p][e]      = sinf(pr);
    feat[s][p][24 + e] = cosf(pr);
  }
  __syncthreads();

  {
    float w[NFEAT];
    #pragma unroll
    for (int k = 0; k < NFEAT; ++k) w[k] = pe_w[k * HALFD + tid];
    const float bv = pe_b[tid];
    #pragma unroll
    for (int half = 0; half < 2; ++half){
      for (int p = 0; p < 16; ++p){
        float acc = bv;
        #pragma unroll
        for (int k = 0; k < NFEAT; ++k) acc = fmaf(feat[half][p][k], w[k], acc);
        outb[p][half * HALFD + tid] = acc;
      }
    }
  }
  __syncthreads();

  const int lane = tid & 63, wv = tid >> 6;
  for (int pp = 0; pp < 4; ++pp){
    const int p = (wv << 2) + pp;
    const size_t gp = (size_t)p0 + p;
    float x[8];
    #pragma unroll
    for (int j = 0; j < 8; ++j) x[j] = outb[p][lane + (j << 6)];
    float s = 0.f;
    #pragma unroll
    for (int j = 0; j < 8; ++j) s += x[j];
    for (int o = 32; o; o >>= 1) s += __shfl_xor(s, o, 64);
    const float m = s * (1.0f / 512.0f);
    float s2 = 0.f;
    #pragma unroll
    for (int j = 0; j < 8; ++j){ const float d = x[j] - m; s2 = fmaf(d, d, s2); }
    for (int o = 32; o; o >>= 1) s2 += __shfl_xor(s2, o, 64);
    const float inv = 1.0f / sqrtf(s2 * (1.0f / 512.0f) + 1e-5f);
    #pragma unroll
    for (int j = 0; j < 8; ++j){
      const int c = lane + (j << 6);
      const float r = (x[j] - m) * inv * ln_g[c] + ln_b[c];
      const size_t o2 = gp * DIMV + c;
      if (WRITE_EMB) emb[o2] = f2bf(x[j]);
      lnout[o2] = f2bf(r);
    }
  }
}

template<bool GATHER, bool WRITE_EMB>
__global__ __launch_bounds__(256) void embed_kernel(
    const float* __restrict__ pc, const float* __restrict__ pc2,
    const int* __restrict__ idx,
    const float* __restrict__ basis, const float* __restrict__ pe_w,
    const float* __restrict__ pe_b,
    const float* __restrict__ ln_g, const float* __restrict__ ln_b,
    bfu* __restrict__ emb, bfu* __restrict__ lnout, int nppbt)
{
  __shared__ float feat[2][16][NFEAT + 1];
  __shared__ float outb[16][DIMV];
  embed_body<GATHER, WRITE_EMB>(blockIdx.x, threadIdx.x, pc, pc2, idx, basis,
      pe_w, pe_b, ln_g, ln_b, emb, lnout, nppbt, feat, outb);
}

// ---------------------------------------------------------------------------
// Transpose body (weights only): in [R][C] fp32 -> out bf16 [C][R].
// ---------------------------------------------------------------------------
template<typename TIN>
__device__ __forceinline__ void transp_body(
    const TIN* __restrict__ in, bfu* __restrict__ out, int R, int C,
    int bx, int by, bfu (*t)[33])
{
  const int c0 = bx * 32, r0 = by * 32;
  const int tx = threadIdx.x & 31, ty = threadIdx.x >> 5;
  #pragma unroll
  for (int rr = ty; rr < 32; rr += 8)
    t[rr][tx] = to_bfu(in[(size_t)(r0 + rr) * C + c0 + tx]);
  __syncthreads();
  #pragma unroll
  for (int rr = ty; rr < 32; rr += 8)
    out[(size_t)(c0 + rr) * R + r0 + tx] = t[tx][rr];
}

// ---------------------------------------------------------------------------
// fused_pre: one launch hiding FPS-independent work under FPS's shadow.
// Blocks [0,16): FPS. [16,784): context embed group 0 -> c_grp.
// [784,4880): the 5 weight transposes.
// ---------------------------------------------------------------------------
__global__ __attribute__((amdgpu_waves_per_eu(1, 1)))
__launch_bounds__(256) void fused_pre(
    const float* __restrict__ pc, const float* __restrict__ pc2,
    int* __restrict__ idx_out,
    const float* __restrict__ basis, const float* __restrict__ pe_w,
    const float* __restrict__ pe_b,
    const float* __restrict__ lnc_g, const float* __restrict__ lnc_b,
    bfu* __restrict__ c_grp,
    const float* __restrict__ wq, const float* __restrict__ wkv,
    const float* __restrict__ wo, const float* __restrict__ w1,
    const float* __restrict__ w2,
    bfu* __restrict__ wqT, bfu* __restrict__ wkvT, bfu* __restrict__ woT,
    bfu* __restrict__ w1T, bfu* __restrict__ w2T)
{
  __shared__ __align__(16) char smem[39424];  // max(fps 32832, embed 39424, transp 2112)
  const int bid = blockIdx.x, tid = threadIdx.x;

  if (bid < NB){
    #pragma clang fp contract(off)
    float4* pts = (float4*)smem;
    int (*mbuf)[8] = (int(*)[8])(smem + 32768);
    fps_body(bid, tid, pc, idx_out, pts, mbuf);
    return;
  }
  const int rb = bid - NB;
  if (rb < GROWS / 16){
    embed_body<false, false>(rb, tid, pc, pc2, nullptr, basis, pe_w, pe_b,
                             lnc_g, lnc_b, nullptr, c_grp, NCTX,
                             (float(*)[16][NFEAT + 1])smem,
                             (float(*)[DIMV])(smem + 6656));
    return;
  }
  int tb = rb - GROWS / 16;
  bfu (*tile)[33] = (bfu(*)[33])smem;
  if (tb < 256){ transp_body<float>(wq,  wqT,  512,  512, tb & 15,  tb >> 4, tile); return; }
  tb -= 256;
  if (tb < 512){ transp_body<float>(wkv, wkvT, 512, 1024, tb & 31,  tb >> 5, tile); return; }
  tb -= 512;
  if (tb < 256){ transp_body<float>(wo,  woT,  512,  512, tb & 15,  tb >> 4, tile); return; }
  tb -= 256;
  if (tb < 2048){ transp_body<float>(w1, w1T,  512, 4096, tb & 127, tb >> 7, tile); return; }
  tb -= 2048;
  transp_body<float>(w2, w2T, 2048, 512, tb & 15, tb >> 4, tile);
}

// ---------------------------------------------------------------------------
// MFMA GEMM: C[M][N] = A[M][K] * B[N][K]^T, bf16 inputs.
// Tile = (FH*32)^2: FH=4 -> 128x128, FH=2 -> 64x64. 4 waves 2x2.
// global_load_lds width=16 staging (R6) + KSTEP-deep barrier amortization
// (R7). LDS linear [BT][KSTEP]; 2-way-max bank conflicts via XOR chunk
// swizzle (inverse on per-lane GLOBAL source + same XOR on ds_read).
// ---------------------------------------------------------------------------
#define EPI_NONE     0
#define EPI_SPLIT    1
#define EPI_SCALE    2
#define EPI_BIAS_RES 3

template<int FH, int KSTEP, typename TC, typename TR, int EPI>
__global__ __launch_bounds__(256, 2) void gemm_mfma(
    const bfu* __restrict__ A, const bfu* __restrict__ B,
    TC* __restrict__ C, TC* __restrict__ C2,
    const float* __restrict__ bias, const TR* __restrict__ res,
    float scale, int N, int K, int lda, int ldb, int ldc,
    long long sA, long long sB, long long sC)
{
  constexpr int BT  = FH * 32;             // block tile edge
  constexpr int CPR = KSTEP / 8;           // 16B chunks per row
  constexpr int NI  = (BT * CPR) / 256;    // chunk issues per wave per matrix
  const int bz = blockIdx.z;
  A += (size_t)bz * sA;
  B += (size_t)bz * sB;
  const size_t coff = (size_t)bz * sC;

  __shared__ __align__(16) short As[BT * KSTEP];
  __shared__ __align__(16) short Bs[BT * KSTEP];

  const int tid = threadIdx.x;
  const int lane = tid & 63, w = tid >> 6;
  const int wl = (w << 6) + lane;
  const int m0 = blockIdx.y * BT, n0 = blockIdx.x * BT;
  const int wm = (w & 1) * (FH * 16), wn = (w >> 1) * (FH * 16);
  const int fr = lane & 15, quad = lane >> 4;

  f32x4 acc[FH][FH];
  #pragma unroll
  for (int i = 0; i < FH; ++i)
    #pragma unroll
    for (int j = 0; j < FH; ++j)
      #pragma unroll
      for (int r = 0; r < 4; ++r) acc[i][j][r] = 0.f;

  for (int k0 = 0; k0 < K; k0 += KSTEP){
    #pragma unroll
    for (int i = 0; i < NI; ++i){
      const int ch = i * 256 + wl;         // stored chunk: row r, slot cs
      const int r  = ch / CPR, cs = ch & (CPR - 1);
      const int cg = cs ^ swzr<KSTEP>(r);  // global chunk (inverse swizzle)
      short* la = (short*)As + ((i * 256 + (w << 6)) << 3); // wave-uniform
      short* lb = (short*)Bs + ((i * 256 + (w << 6)) << 3);
      GLD16(A + (size_t)(m0 + r) * lda + k0 + cg * 8, la);
      GLD16(B + (size_t)(n0 + r) * ldb + k0 + cg * 8, lb);
    }
    __syncthreads();
    #pragma unroll
    for (int kk = 0; kk < KSTEP / 32; ++kk){
      bf16x8 af[FH], bf[FH];
      #pragma unroll
      for (int i = 0; i < FH; ++i){
        const int row = wm + i * 16 + fr;
        const int cl = (kk * 4 + quad) ^ swzr<KSTEP>(row);
        af[i] = *(const bf16x8*)&As[row * KSTEP + (cl << 3)];
      }
      #pragma unroll
      for (int j = 0; j < FH; ++j){
        const int row = wn + j * 16 + fr;
        const int cl = (kk * 4 + quad) ^ swzr<KSTEP>(row);
        bf[j] = *(const bf16x8*)&Bs[row * KSTEP + (cl << 3)];
      }
      #pragma unroll
      for (int i = 0; i < FH; ++i)
        #pragma unroll
        for (int j = 0; j < FH; ++j)
          acc[i][j] = __builtin_amdgcn_mfma_f32_16x16x32_bf16(af[i], bf[j], acc[i][j], 0, 0, 0);
    }
    __syncthreads();
  }

  // C/D layout: col = lane&15, row = quad*4 + reg
  TC* Cp = C + coff;
  #pragma unroll
  for (int i = 0; i < FH; ++i){
    #pragma unroll
    for (int r = 0; r < 4; ++r){
      const int cm = m0 + wm + i * 16 + quad * 4 + r;
      #pragma unroll
      for (int j = 0; j < FH; ++j){
        const int cn = n0 + wn + j * 16 + fr;
        float v = acc[i][j][r];
        if (EPI == EPI_SCALE)    v *= scale;
        if (EPI == EPI_BIAS_RES) v = v + bias[cn] + loadE(&res[coff + (size_t)cm * ldc + cn]);
        if (EPI == EPI_SPLIT){
          const int half = N >> 1;
          if (cn < half) storeE(&C [(size_t)cm * half + cn],          v);
          else           storeE(&C2[(size_t)cm * half + (cn - half)], v);
        } else {
          storeE(&Cp[(size_t)cm * ldc + cn], v);
        }
      }
    }
  }
}

// ---------------------------------------------------------------------------
// kv_mfma: fused same-shape GEMM launch (all FH=4, KSTEP=64, EPI_NONE,
// bf16 out, K=512, lda=ldb=512). Linear block decode:
//   [0, nq):        q  = q_in @ wqT    (nq = 768 for group 0, else 0)
//   [nq, nq+384):   k  = c   @ wkT     (wkvT rows 0..511)
//   [nq+384, +768): vT = wvT @ cT      (64 blocks per bt, 6 bt)
// R10: -1 launch per group (+q for g0), better CU fill, shared c_grp L2
// locality. Outputs disjoint; inputs read-only -> race-free. (R11 measured
// ~-20us vs separate launches.)
// ---------------------------------------------------------------------------
__global__ __launch_bounds__(256, 2) void kv_mfma(
    int nq,
    const bfu* __restrict__ qA, const bfu* __restrict__ qB, bfu* __restrict__ qC,
    const bfu* __restrict__ cg, const bfu* __restrict__ wkvT,
    bfu* __restrict__ kg, bfu* __restrict__ vg)
{
  constexpr int KSTEP = 64, CPR = 8, NI = 4;
  const bfu *A, *B; bfu *C; int m0, n0, ldc;
  {
    int bid = blockIdx.x;
    if (bid < nq){
      A = qA; B = qB; C = qC;
      m0 = (bid >> 2) * 128; n0 = (bid & 3) * 128; ldc = 512;
    } else {
      bid -= nq;
      if (bid < 384){
        A = cg; B = wkvT; C = kg;
        m0 = (bid >> 2) * 128; n0 = (bid & 3) * 128; ldc = 512;
      } else {
        const int r = bid - 384, z = r >> 6, rr = r & 63;
        A = wkvT + 512 * 512;
        B = cg + (size_t)z * 1048576;
        C = vg + (size_t)z * 1048576;
        m0 = (rr >> 4) * 128; n0 = (rr & 15) * 128; ldc = 2048;
      }
    }
  }

  __shared__ __align__(16) short As[128 * KSTEP];
  __shared__ __align__(16) short Bs[128 * KSTEP];

  const int tid = threadIdx.x;
  const int lane = tid & 63, w = tid >> 6;
  const int wl = (w << 6) + lane;
  const int wm = (w & 1) * 64, wn = (w >> 1) * 64;
  const int fr = lane & 15, quad = lane >> 4;

  f32x4 acc[4][4];
  #pragma unroll
  for (int i = 0; i < 4; ++i)
    #pragma unroll
    for (int j = 0; j < 4; ++j)
      #pragma unroll
      for (int r = 0; r < 4; ++r) acc[i][j][r] = 0.f;

  for (int k0 = 0; k0 < 512; k0 += KSTEP){
    #pragma unroll
    for (int i = 0; i < NI; ++i){
      const int ch = i * 256 + wl;
      const int r  = ch / CPR, cs = ch & (CPR - 1);
      const int cg2 = cs ^ swzr<KSTEP>(r);
      short* la = (short*)As + ((i * 256 + (w << 6)) << 3);
      short* lb = (short*)Bs + ((i * 256 + (w << 6)) << 3);
      GLD16(A + (size_t)(m0 + r) * 512 + k0 + cg2 * 8, la);
      GLD16(B + (size_t)(n0 + r) * 512 + k0 + cg2 * 8, lb);
    }
    __syncthreads();
    #pragma unroll
    for (int kk = 0; kk < KSTEP / 32; ++kk){
      bf16x8 af[4], bf[4];
      #pragma unroll
      for (int i = 0; i < 4; ++i){
        const int row = wm + i * 16 + fr;
        const int cl = (kk * 4 + quad) ^ swzr<KSTEP>(row);
        af[i] = *(const bf16x8*)&As[row * KSTEP + (cl << 3)];
      }
      #pragma unroll
      for (int j = 0; j < 4; ++j){
        const int row = wn + j * 16 + fr;
        const int cl = (kk * 4 + quad) ^ swzr<KSTEP>(row);
        bf[j] = *(const bf16x8*)&Bs[row * KSTEP + (cl << 3)];
      }
      #pragma unroll
      for (int i = 0; i < 4; ++i)
        #pragma unroll
        for (int j = 0; j < 4; ++j)
          acc[i][j] = __builtin_amdgcn_mfma_f32_16x16x32_bf16(af[i], bf[j], acc[i][j], 0, 0, 0);
    }
    __syncthreads();
  }

  #pragma unroll
  for (int i = 0; i < 4; ++i){
    #pragma unroll
    for (int r = 0; r < 4; ++r){
      const int cm = m0 + wm + i * 16 + quad * 4 + r;
      #pragma unroll
      for (int j = 0; j < 4; ++j){
        const int cn = n0 + wn + j * 16 + fr;
        C[(size_t)cm * ldc + cn] = f2bf(acc[i][j][r]);
      }
    }
  }
}

// ---------------------------------------------------------------------------
// Fused MLP1 + exact GeLU (MFMA): act = (A@w1T[a]+b1a) * gelu(A@w1T[g]+b1g).
// Same global_load_lds + XOR-swizzle staging, KSTEP=64.
// ---------------------------------------------------------------------------
__global__ __launch_bounds__(256, 1) void mlp1_mfma(
    const bfu* __restrict__ A, const bfu* __restrict__ B,  // B = w1T [4096][512]
    const float* __restrict__ b1, bfu* __restrict__ act)
{
  constexpr int KSTEP = 64, CPR = 8, NI = 4;
  __shared__ __align__(16) short As[128 * KSTEP];
  __shared__ __align__(16) short Ba[128 * KSTEP];
  __shared__ __align__(16) short Bg[128 * KSTEP];

  const int tid = threadIdx.x;
  const int lane = tid & 63, w = tid >> 6;
  const int wl = (w << 6) + lane;
  const int m0 = blockIdx.y * 128, n0 = blockIdx.x * 128;
  const int wm = (w & 1) * 64, wn = (w >> 1) * 64;
  const int fr = lane & 15, quad = lane >> 4;

  f32x4 acca[4][4], accg[4][4];
  #pragma unroll
  for (int i = 0; i < 4; ++i)
    #pragma unroll
    for (int j = 0; j < 4; ++j)
      #pragma unroll
      for (int r = 0; r < 4; ++r){ acca[i][j][r] = 0.f; accg[i][j][r] = 0.f; }

  for (int k0 = 0; k0 < 512; k0 += KSTEP){
    #pragma unroll
    for (int i = 0; i < NI; ++i){
      const int ch = i * 256 + wl;
      const int r  = ch / CPR, cs = ch & (CPR - 1);
      const int cg = cs ^ swzr<KSTEP>(r);
      short* da = (short*)As + ((i * 256 + (w << 6)) << 3);
      short* db = (short*)Ba + ((i * 256 + (w << 6)) << 3);
      short* dg = (short*)Bg + ((i * 256 + (w << 6)) << 3);
      GLD16(A + (size_t)(m0 + r) * 512 + k0 + cg * 8, da);
      GLD16(B + (size_t)(n0 + r) * 512 + k0 + cg * 8, db);
      GLD16(B + (size_t)(n0 + 2048 + r) * 512 + k0 + cg * 8, dg);
    }
    __syncthreads();
    #pragma unroll
    for (int kk = 0; kk < KSTEP / 32; ++kk){
      bf16x8 af[4], ba[4], bg[4];
      #pragma unroll
      for (int i = 0; i < 4; ++i){
        const int row = wm + i * 16 + fr;
        const int cl = (kk * 4 + quad) ^ swzr<KSTEP>(row);
        af[i] = *(const bf16x8*)&As[row * KSTEP + (cl << 3)];
      }
      #pragma unroll
      for (int j = 0; j < 4; ++j){
        const int row = wn + j * 16 + fr;
        const int cl = (kk * 4 + quad) ^ swzr<KSTEP>(row);
        ba[j] = *(const bf16x8*)&Ba[row * KSTEP + (cl << 3)];
        bg[j] = *(const bf16x8*)&Bg[row * KSTEP + (cl << 3)];
      }
      #pragma unroll
      for (int i = 0; i < 4; ++i)
        #pragma unroll
        for (int j = 0; j < 4; ++j){
          acca[i][j] = __builtin_amdgcn_mfma_f32_16x16x32_bf16(af[i], ba[j], acca[i][j], 0, 0, 0);
          accg[i][j] = __builtin_amdgcn_mfma_f32_16x16x32_bf16(af[i], bg[j], accg[i][j], 0, 0, 0);
        }
    }
    __syncthreads();
  }

  #pragma unroll
  for (int i = 0; i < 4; ++i){
    #pragma unroll
    for (int r = 0; r < 4; ++r){
      const int cm = m0 + wm + i * 16 + quad * 4 + r;
      #pragma unroll
      for (int j = 0; j < 4; ++j){
        const int cn = n0 + wn + j * 16 + fr;
        const float a = acca[i][j][r] + b1[cn];
        const float g = accg[i][j][r] + b1[cn + 2048];
        const float ge = g * 0.5f * (1.0f + erff(g * 0.70710678118654752f));
        act[(size_t)cm * 2048 + cn] = f2bf(a * ge);
      }
    }
  }
}

// ---------------------------------------------------------------------------
// Row softmax over 2048 bf16 logits, in place.
// ---------------------------------------------------------------------------
__global__ __launch_bounds__(256) void softmax_kernel(bfu* __restrict__ sc){
  __shared__ float red[4];
  const int tid = threadIdx.x;
  const int lane = tid & 63, wv = tid >> 6;
  bfu* rp = sc + (size_t)blockIdx.x * NCTX;
  float x[8];
  #pragma unroll
  for (int j = 0; j < 8; ++j) x[j] = bf2f(rp[tid + (j << 8)]);
  float mx = x[0];
  #pragma unroll
  for (int j = 1; j < 8; ++j) mx = fmaxf(mx, x[j]);
  for (int o = 32; o; o >>= 1) mx = fmaxf(mx, __shfl_xor(mx, o, 64));
  if (lane == 0) red[wv] = mx;
  __syncthreads();
  mx = fmaxf(fmaxf(red[0], red[1]), fmaxf(red[2], red[3]));
  float sum = 0.f;
  #pragma unroll
  for (int j = 0; j < 8; ++j){ x[j] = __expf(x[j] - mx); sum += x[j]; }
  for (int o = 32; o; o >>= 1) sum += __shfl_xor(sum, o, 64);
  __syncthreads();
  if (lane == 0) red[wv] = sum;
  __syncthreads();
  sum = red[0] + red[1] + red[2] + red[3];
  const float inv = 1.0f / sum;
  #pragma unroll
  for (int j = 0; j < 8; ++j) rp[tid + (j << 8)] = f2bf(x[j] * inv);
}

// ---------------------------------------------------------------------------
// LayerNorm rows of 512 fp32 -> bf16.
// ---------------------------------------------------------------------------
__global__ __launch_bounds__(256) void ln_kernel(const float* __restrict__ in,
                                                 const float* __restrict__ g,
                                                 const float* __restrict__ b,
                                                 bfu* __restrict__ out){
  const int tid = threadIdx.x, lane = tid & 63, wv = tid >> 6;
  const size_t row = (size_t)blockIdx.x * 4 + wv;
  const float* rp = in + row * DIMV;
  float x[8];
  #pragma unroll
  for (int j = 0; j < 8; ++j) x[j] = rp[lane + (j << 6)];
  float s = 0.f;
  #pragma unroll
  for (int j = 0; j < 8; ++j) s += x[j];
  for (int o = 32; o; o >>= 1) s += __shfl_xor(s, o, 64);
  const float m = s * (1.0f / 512.0f);
  float s2 = 0.f;
  #pragma unroll
  for (int j = 0; j < 8; ++j){ const float d = x[j] - m; s2 = fmaf(d, d, s2); }
  for (int o = 32; o; o >>= 1) s2 += __shfl_xor(s2, o, 64);
  const float inv = 1.0f / sqrtf(s2 * (1.0f / 512.0f) + 1e-5f);
  bfu* op = out + row * DIMV;
  #pragma unroll
  for (int j = 0; j < 8; ++j){
    const int c = lane + (j << 6);
    op[c] = f2bf((x[j] - m) * inv * g[c] + b[c]);
  }
}

// ---------------------------------------------------------------------------
// Workspace (peak 121,667,584 B < proven 125,861,888):
//   idx    @ 0          (32 KB)
//   emb_s  @ 32768      (25,165,824) \  act half (50,331,648) aliases
//   q_in   @ 25198592   (25,165,824) /  emb_s+q_in (both dead at MLP)
//          q_in -> attnout after q GEMM
//   c_grp  @ 50364416   (12,582,912) -> scores (GRP=6)
//   k_grp  @ 62947328   (12,582,912)
//   v_grp  @ 75530240   (12,582,912) = vT directly (kv split, no transp)
//   qbuf   @ 88113152   (25,165,824) -> lnx
//   wT     @ 113278976  (8,388,608): wqT|wkvT|woT|w1T|w2T
// ---------------------------------------------------------------------------
extern "C" void kernel_launch(void* const* d_in, const int* in_sizes, int n_in,
                              void* d_out, int out_size, void* d_ws, size_t ws_size,
                              hipStream_t stream)
{
  (void)in_sizes; (void)n_in; (void)out_size;
  if (ws_size < 121667584ull) return;

  const float* pc    = (const float*)d_in[0];
  const float* pc2   = (const float*)d_in[1];
  const float* basis = (const float*)d_in[2];
  const float* pe_w  = (const float*)d_in[3];
  const float* pe_b  = (const float*)d_in[4];
  const float* lnq_g = (const float*)d_in[5];
  const float* lnq_b = (const float*)d_in[6];
  const float* lnc_g = (const float*)d_in[7];
  const float* lnc_b = (const float*)d_in[8];
  const float* wq    = (const float*)d_in[9];
  const float* wkv   = (const float*)d_in[10];
  const float* wo    = (const float*)d_in[11];
  const float* bo    = (const float*)d_in[12];
  const float* lnf_g = (const float*)d_in[13];
  const float* lnf_b = (const float*)d_in[14];
  const float* w1    = (const float*)d_in[15];
  const float* b1    = (const float*)d_in[16];
  const float* w2    = (const float*)d_in[17];
  const float* b2    = (const float*)d_in[18];
  float* xout = (float*)d_out;

  char* ws = (char*)d_ws;
  int* idxb   = (int*)(ws);
  bfu* emb_s  = (bfu*)(ws + 32768);
  bfu* q_in   = (bfu*)(ws + 25198592);
  bfu* c_grp  = (bfu*)(ws + 50364416);
  bfu* k_grp  = (bfu*)(ws + 62947328);
  bfu* v_grp  = (bfu*)(ws + 75530240);
  bfu* qbuf   = (bfu*)(ws + 88113152);
  bfu* wqT    = (bfu*)(ws + 113278976);
  bfu* wkvT   = (bfu*)(ws + 113803264);
  bfu* woT    = (bfu*)(ws + 114851840);
  bfu* w1T    = (bfu*)(ws + 115376128);
  bfu* w2T    = (bfu*)(ws + 119570432);
  bfu* scores  = c_grp;     // after c consumed by k/vT GEMMs
  bfu* vT      = v_grp;     // written transposed directly
  bfu* attnout = q_in;      // after q GEMM consumed q_in
  bfu* lnx     = qbuf;      // after attention consumed q
  bfu* actb    = emb_s;     // spans emb_s+q_in (one MLP half at a time)

  // 0+1. fused: FPS || {weight transposes, group-0 context embed}
  fused_pre<<<FUSED_BLKS, 256, 0, stream>>>(
      pc, pc2, idxb, basis, pe_w, pe_b, lnc_g, lnc_b, c_grp,
      wq, wkv, wo, w1, w2, wqT, wkvT, woT, w1T, w2T);

  // 2. latent embed -> emb_s (raw) + q_in (LN'd)   [needs idxb]
  embed_kernel<true, true><<<MROWS/16, 256, 0, stream>>>(
      pc, pc2, idxb, basis, pe_w, pe_b, lnq_g, lnq_b, emb_s, q_in, NLAT);

  // 3/4. per-group context pipeline (GRP=6, 8 groups; g0 embed done in
  // fused_pre; q GEMM fused into g0's kv launch)
  for (int g = 0; g < NGRP; ++g){
    const int bt0 = g * GRP;
    if (g > 0){
      embed_kernel<false, false><<<GROWS/16, 256, 0, stream>>>(
          pc + (size_t)bt0 * NCTX * 3, pc2 + (size_t)bt0 * NCTX * 3, nullptr,
          basis, pe_w, pe_b, lnc_g, lnc_b, nullptr, c_grp, NCTX);
    }

    // fused {q (g0 only)} + {k = c @ wkT} + {vT = wvT @ cT}
    const int nq = (g == 0) ? 768 : 0;
    kv_mfma<<<nq + 768, 256, 0, stream>>>(
        nq, q_in, wqT, qbuf, c_grp, wkvT, k_grp, v_grp);

    // scores = (q @ k^T) * scale (overwrites c_grp region)
    gemm_mfma<4, 64, bfu, float, EPI_SCALE><<<dim3(16, 4, GRP), 256, 0, stream>>>(
        qbuf + (size_t)bt0 * 262144, k_grp, scores, nullptr, nullptr, nullptr,
        0.044194173824159216f,
        2048, 512, 512, 512, 2048, 262144, 1048576, 1048576);

    softmax_kernel<<<GRP * 512, 256, 0, stream>>>(scores);

    // attnout = P @ V : 64x64 tiles, KSTEP=128
    gemm_mfma<2, 128, bfu, float, EPI_NONE><<<dim3(8, 8, GRP), 256, 0, stream>>>(
        scores, vT, attnout + (size_t)bt0 * 262144, nullptr, nullptr, nullptr, 1.0f,
        512, 2048, 2048, 2048, 512, 1048576, 1048576, 262144);
  }

  // 5. x = attnout @ wo + bo + emb_s -> d_out (fp32)
  gemm_mfma<4, 64, float, bfu, EPI_BIAS_RES><<<dim3(4, 192, 1), 256, 0, stream>>>(
      attnout, woT, xout, nullptr, bo, emb_s, 1.0f,
      512, 512, 512, 512, 512, 0, 0, 0);

  // 6. lnx = LN(x)
  ln_kernel<<<MROWS/4, 256, 0, stream>>>(xout, lnf_g, lnf_b, lnx);

  // 7/8. MLP in two row-halves (act buffer holds one half)
  for (int h = 0; h < 2; ++h){
    const size_t ro = (size_t)h * 12288;
    mlp1_mfma<<<dim3(16, 96, 1), 256, 0, stream>>>(
        lnx + ro * 512, w1T, b1, actb);
    gemm_mfma<4, 64, float, float, EPI_BIAS_RES><<<dim3(4, 96, 1), 256, 0, stream>>>(
        actb, w2T, xout + ro * 512, nullptr, b2, xout + ro * 512, 1.0f,
        512, 2048, 2048, 2048, 512, 0, 0, 0);
  }
}